// Round 22
// baseline (611.485 us; speedup 1.0000x reference)
//
#include <hip/hip_runtime.h>
#include <hip/hip_fp16.h>
#include <math.h>

#define N_NODES 16384
#define N_EDGES 524288
#define N_GRAPHS 64
#define HID 128
#define FILT 128
#define NG 51
#define NL 6
#define TROWS 2048   // filter-table resolution
#define DMAX 8.66025404f          // 5*sqrt(3), max possible distance
#define DSTEP (DMAX / (TROWS - 1))
#define INV_DSTEP ((TROWS - 1) / DMAX)
#define EU 3         // edge-pair unroll (6 edges in flight)
#define TSTRIDE 132  // fp32 LDS row stride (tab2)
#define TP 136       // fp16 LDS row stride (node MFMA tiles)

typedef _Float16 half8 __attribute__((ext_vector_type(8)));
typedef float f32x4 __attribute__((ext_vector_type(4)));

__device__ __forceinline__ float ssp(float x) {
    float sp = (x > 20.0f) ? x : log1pf(__expf(x));
    return sp - 0.6931471805599453f;
}

__global__ void k_embed(const int* __restrict__ z, const float* __restrict__ emb,
                        float* __restrict__ h) {
    int i = blockIdx.x * blockDim.x + threadIdx.x;
    int n = i >> 7, c = i & 127;
    h[i] = emb[z[n] * HID + c];
}

__global__ void k_hist(const int* __restrict__ ei, int* __restrict__ cnt) {
    int e = blockIdx.x * blockDim.x + threadIdx.x;
    if (e < N_EDGES) atomicAdd(&cnt[ei[e]], 1);
}

__global__ __launch_bounds__(1024) void k_scan(const int* __restrict__ cnt,
                                               int* __restrict__ rowptr,
                                               int* __restrict__ wo) {
    __shared__ int sums[1024];
    int t = threadIdx.x;
    int loc[16];
    int s = 0;
    #pragma unroll
    for (int i = 0; i < 16; ++i) { loc[i] = cnt[t * 16 + i]; s += loc[i]; }
    sums[t] = s;
    __syncthreads();
    for (int off = 1; off < 1024; off <<= 1) {
        int v = sums[t];
        int u = (t >= off) ? sums[t - off] : 0;
        __syncthreads();
        sums[t] = v + u;
        __syncthreads();
    }
    int ex = sums[t] - s;
    #pragma unroll
    for (int i = 0; i < 16; ++i) {
        rowptr[t * 16 + i] = ex;
        wo[t * 16 + i] = ex;
        ex += loc[i];
    }
    if (t == 1023) rowptr[16384] = ex;
}

// scatter into CSR order: meta.x = col, meta.y = ew bits
__global__ void k_scatter(const int* __restrict__ ei, const float* __restrict__ pos,
                          int* __restrict__ wo, int2* __restrict__ meta) {
    int e = blockIdx.x * blockDim.x + threadIdx.x;
    if (e >= N_EDGES) return;
    int r = ei[e], c = ei[N_EDGES + e];
    int p = atomicAdd(&wo[r], 1);
    float dx = pos[r * 3 + 0] - pos[c * 3 + 0];
    float dy = pos[r * 3 + 1] - pos[c * 3 + 1];
    float dz = pos[r * 3 + 2] - pos[c * 3 + 2];
    float ew = sqrtf(dx * dx + dy * dy + dz * dz);
    meta[p] = make_int2(c, __float_as_int(ew));
}

// Pack W[128k][128c] fp32 into MFMA B-fragment order (fp16):
// dst[mat][((kk*8+n)*64+lane)*8 + j] = W[32kk + (lane>>4)*8 + j][16n + (lane&15)]
__global__ void k_wpack(const float* __restrict__ src, __half* __restrict__ dst,
                        int nmat) {
    int idx = blockIdx.x * 256 + threadIdx.x;
    if (idx >= nmat * 2048) return;
    int mat = idx >> 11;
    int r = idx & 2047;
    int kk = r >> 9, n = (r >> 6) & 7, lane = r & 63;
    const float* S = src + (size_t)mat * 16384;
    __half* D = dst + (size_t)mat * 16384 + (size_t)r * 8;
    int k0 = kk * 32 + (lane >> 4) * 8;
    int c = n * 16 + (lane & 15);
    #pragma unroll
    for (int j = 0; j < 8; ++j)
        D[j] = __float2half_rn(S[(k0 + j) * 128 + c]);
}

// Filter tables, wave = 4 rows x 128 channels (lane = channel); fp16 output.
__global__ __launch_bounds__(256, 4) void k_tab2(
    const float* __restrict__ mlp1_w, const float* __restrict__ mlp1_b,
    const float* __restrict__ mlp2_w, const float* __restrict__ mlp2_b,
    __half* __restrict__ ftab)
{
    __shared__ float tls[4 * 4 * TSTRIDE];
    const int w = threadIdx.x >> 6;
    const int lane = threadIdx.x & 63;
    const int gr = blockIdx.x * 16 + w * 4;
    const int layer = gr >> 11;
    const int r0 = gr & (TROWS - 1);
    const float* W1 = mlp1_w + (size_t)layer * NG * FILT;
    const float* B1 = mlp1_b + (size_t)layer * FILT;
    const float* W2 = mlp2_w + (size_t)layer * FILT * FILT;
    const float* B2 = mlp2_b + (size_t)layer * FILT;
    float* tp = &tls[w * 4 * TSTRIDE];
    float acc1[4][2];
    {
        float ba = B1[lane], bb = B1[lane + 64];
        #pragma unroll
        for (int j = 0; j < 4; ++j) { acc1[j][0] = ba; acc1[j][1] = bb; }
    }
    for (int k = 0; k < NG; ++k) {
        float wa = W1[k * FILT + lane];
        float wb = W1[k * FILT + lane + 64];
        #pragma unroll
        for (int j = 0; j < 4; ++j) {
            float dd = (float)(r0 + j) * DSTEP - 0.2f * (float)k;
            float g = __expf(-12.5f * dd * dd);
            acc1[j][0] = fmaf(g, wa, acc1[j][0]);
            acc1[j][1] = fmaf(g, wb, acc1[j][1]);
        }
    }
    #pragma unroll
    for (int j = 0; j < 4; ++j) {
        tp[j * TSTRIDE + lane] = ssp(acc1[j][0]);
        tp[j * TSTRIDE + lane + 64] = ssp(acc1[j][1]);
    }
    __syncthreads();
    float acc2[4][2];
    {
        float ba = B2[lane], bb = B2[lane + 64];
        #pragma unroll
        for (int j = 0; j < 4; ++j) { acc2[j][0] = ba; acc2[j][1] = bb; }
    }
    #pragma unroll 4
    for (int k = 0; k < FILT; k += 2) {
        float w0a = W2[k * FILT + lane];
        float w0b = W2[k * FILT + lane + 64];
        float w1a = W2[(k + 1) * FILT + lane];
        float w1b = W2[(k + 1) * FILT + lane + 64];
        #pragma unroll
        for (int j = 0; j < 4; ++j) {
            float2 t = *(float2*)&tp[j * TSTRIDE + k];
            acc2[j][0] = fmaf(t.x, w0a, fmaf(t.y, w1a, acc2[j][0]));
            acc2[j][1] = fmaf(t.x, w0b, fmaf(t.y, w1b, acc2[j][1]));
        }
    }
    #pragma unroll
    for (int j = 0; j < 4; ++j) {
        float d = (float)(r0 + j) * DSTEP;
        float C = 0.5f * (__cosf(d * 0.31415926535f) + 1.0f);
        __half* out = ftab + (size_t)layer * TROWS * FILT + (size_t)(r0 + j) * FILT;
        out[lane] = __float2half_rn(acc2[j][0] * C);
        out[lane + 64] = __float2half_rn(acc2[j][1] * C);
    }
}

// Half-wave-paired edge aggregation; xh/tab fp16 in, agg fp16 OUT.
__global__ __launch_bounds__(256, 7) void k_edge9(
    const int2* __restrict__ meta, const int* __restrict__ rowptr,
    const __half* __restrict__ xh, const __half* __restrict__ tab,
    __half* __restrict__ agg)
{
    const int row = blockIdx.x * 4 + (threadIdx.x >> 6);
    const int lane = threadIdx.x & 63;
    const int half = lane >> 5;
    const int c4 = (lane & 31) * 4;
    const int es = rowptr[row], ee = rowptr[row + 1];
    float4 acc = make_float4(0.f, 0.f, 0.f, 0.f);
    if (es < ee) {
        int2 mcur[EU];
        #pragma unroll
        for (int u = 0; u < EU; ++u)
            mcur[u] = meta[min(es + 2 * u + half, ee - 1)];
        for (int e = es; e < ee; e += 2 * EU) {
            const int en = e + 2 * EU;
            int2 mnext[EU];
            if (en < ee) {
                #pragma unroll
                for (int u = 0; u < EU; ++u)
                    mnext[u] = meta[min(en + 2 * u + half, ee - 1)];
            }
            float2 t0h[EU], t1h[EU], xr[EU];
            float f[EU], sc[EU];
            #pragma unroll
            for (int u = 0; u < EU; ++u) {
                sc[u] = (e + 2 * u + half < ee) ? 1.f : 0.f;
                float d = __int_as_float(mcur[u].y);
                float uu = d * INV_DSTEP;
                int i0 = min((int)uu, TROWS - 2);
                f[u] = uu - (float)i0;
                t0h[u] = *(const float2*)&tab[(size_t)i0 * FILT + c4];
                t1h[u] = *(const float2*)&tab[(size_t)(i0 + 1) * FILT + c4];
                xr[u]  = *(const float2*)&xh[(size_t)mcur[u].x * FILT + c4];
            }
            #pragma unroll
            for (int u = 0; u < EU; ++u) {
                float2 T0a = __half22float2(*reinterpret_cast<__half2*>(&t0h[u].x));
                float2 T0b = __half22float2(*reinterpret_cast<__half2*>(&t0h[u].y));
                float2 T1a = __half22float2(*reinterpret_cast<__half2*>(&t1h[u].x));
                float2 T1b = __half22float2(*reinterpret_cast<__half2*>(&t1h[u].y));
                float2 x01 = __half22float2(*reinterpret_cast<__half2*>(&xr[u].x));
                float2 x23 = __half22float2(*reinterpret_cast<__half2*>(&xr[u].y));
                acc.x = fmaf(fmaf(f[u], T1a.x - T0a.x, T0a.x) * sc[u], x01.x, acc.x);
                acc.y = fmaf(fmaf(f[u], T1a.y - T0a.y, T0a.y) * sc[u], x01.y, acc.y);
                acc.z = fmaf(fmaf(f[u], T1b.x - T0b.x, T0b.x) * sc[u], x23.x, acc.z);
                acc.w = fmaf(fmaf(f[u], T1b.y - T0b.y, T0b.y) * sc[u], x23.y, acc.w);
            }
            #pragma unroll
            for (int u = 0; u < EU; ++u) mcur[u] = mnext[u];
        }
        acc.x += __shfl_xor(acc.x, 32, 64);
        acc.y += __shfl_xor(acc.y, 32, 64);
        acc.z += __shfl_xor(acc.z, 32, 64);
        acc.w += __shfl_xor(acc.w, 32, 64);
    }
    if (half == 0) {
        float2 st;
        ((__half2*)&st)[0] = __floats2half2_rn(acc.x, acc.y);
        ((__half2*)&st)[1] = __floats2half2_rn(acc.z, acc.w);
        *(float2*)&agg[(size_t)row * FILT + c4] = st;
    }
}

// ---------------------------------------------------------------------------
// MFMA node GEMMs. Block = 64 nodes = 4 waves; wave computes a 16x128 strip
// via mfma_f32_16x16x32_f16 (8 N-tiles x 4 K-steps). A from global fp16 (or
// fp32 + cvt), B from fragment-packed fp16 weights (k_wpack). C/D layout:
// col = lane&15, row = (lane>>4)*4 + q (HW-verified). Inter-GEMM activations
// via wave-private LDS fp16 tile [16][TP].
// ---------------------------------------------------------------------------
template<bool A32, bool RESID, bool G3>
__global__ __launch_bounds__(256, 4) void k_nodeM(
    const __half* __restrict__ Ah, const float* __restrict__ Af,
    const __half* __restrict__ Wp1, const float* __restrict__ B1,
    const __half* __restrict__ Wp2, const float* __restrict__ B2,
    const float* __restrict__ Hin, float* __restrict__ Hout,
    const __half* __restrict__ Wp3, __half* __restrict__ XHout)
{
    __shared__ __half tls[4][16 * TP];
    const int w = threadIdx.x >> 6;
    const int lane = threadIdx.x & 63;
    const int lm = lane & 15;
    const int lk = lane >> 4;
    const int rbase = blockIdx.x * 64 + w * 16;
    __half* tp = &tls[w][0];

    // ---- GEMM1 ----
    f32x4 acc[8];
    #pragma unroll
    for (int n = 0; n < 8; ++n) acc[n] = (f32x4){0.f, 0.f, 0.f, 0.f};
    #pragma unroll
    for (int kk = 0; kk < 4; ++kk) {
        half8 a;
        if (A32) {
            const float* ap = &Af[(size_t)(rbase + lm) * 128 + kk * 32 + lk * 8];
            float4 v0 = *(const float4*)ap;
            float4 v1 = *(const float4*)(ap + 4);
            a[0] = (_Float16)v0.x; a[1] = (_Float16)v0.y;
            a[2] = (_Float16)v0.z; a[3] = (_Float16)v0.w;
            a[4] = (_Float16)v1.x; a[5] = (_Float16)v1.y;
            a[6] = (_Float16)v1.z; a[7] = (_Float16)v1.w;
        } else {
            a = *(const half8*)&Ah[(size_t)(rbase + lm) * 128 + kk * 32 + lk * 8];
        }
        #pragma unroll
        for (int n = 0; n < 8; ++n) {
            half8 b = *(const half8*)&Wp1[((kk * 8 + n) * 64 + lane) * 8];
            acc[n] = __builtin_amdgcn_mfma_f32_16x16x32_f16(a, b, acc[n], 0, 0, 0);
        }
    }
    // epilogue1: bias + ssp -> tp (fp16)
    #pragma unroll
    for (int n = 0; n < 8; ++n) {
        float bv = B1[n * 16 + lm];
        #pragma unroll
        for (int q = 0; q < 4; ++q)
            tp[(lk * 4 + q) * TP + n * 16 + lm] = __float2half_rn(ssp(acc[n][q] + bv));
    }
    __syncthreads();
    // ---- GEMM2 ----
    f32x4 acc2[8];
    #pragma unroll
    for (int n = 0; n < 8; ++n) acc2[n] = (f32x4){0.f, 0.f, 0.f, 0.f};
    #pragma unroll
    for (int kk = 0; kk < 4; ++kk) {
        half8 a = *(const half8*)&tp[lm * TP + kk * 32 + lk * 8];
        #pragma unroll
        for (int n = 0; n < 8; ++n) {
            half8 b = *(const half8*)&Wp2[((kk * 8 + n) * 64 + lane) * 8];
            acc2[n] = __builtin_amdgcn_mfma_f32_16x16x32_f16(a, b, acc2[n], 0, 0, 0);
        }
    }
    __syncthreads();
    // epilogue2: bias (+residual) -> Hout fp32; stage fp16 for GEMM3
    #pragma unroll
    for (int n = 0; n < 8; ++n) {
        float bv = B2[n * 16 + lm];
        #pragma unroll
        for (int q = 0; q < 4; ++q) {
            size_t ro = (size_t)(rbase + lk * 4 + q) * 128 + n * 16 + lm;
            float v = acc2[n][q] + bv;
            if (RESID) v += Hin[ro];
            Hout[ro] = v;
            if (G3) tp[(lk * 4 + q) * TP + n * 16 + lm] = __float2half_rn(v);
        }
    }
    if (G3) {
        __syncthreads();
        f32x4 acc3[8];
        #pragma unroll
        for (int n = 0; n < 8; ++n) acc3[n] = (f32x4){0.f, 0.f, 0.f, 0.f};
        #pragma unroll
        for (int kk = 0; kk < 4; ++kk) {
            half8 a = *(const half8*)&tp[lm * TP + kk * 32 + lk * 8];
            #pragma unroll
            for (int n = 0; n < 8; ++n) {
                half8 b = *(const half8*)&Wp3[((kk * 8 + n) * 64 + lane) * 8];
                acc3[n] = __builtin_amdgcn_mfma_f32_16x16x32_f16(a, b, acc3[n], 0, 0, 0);
            }
        }
        __syncthreads();
        #pragma unroll
        for (int n = 0; n < 8; ++n)
            #pragma unroll
            for (int q = 0; q < 4; ++q)
                tp[(lk * 4 + q) * TP + n * 16 + lm] = __float2half_rn(acc3[n][q]);
        __syncthreads();
        // coalesced fp16 writeback of the wave's 16x128 tile
        #pragma unroll
        for (int it = 0; it < 4; ++it) {
            int idx = it * 64 + lane;
            int row = idx >> 4, k8 = (idx & 15) * 8;
            *(float4*)&XHout[(size_t)(rbase + row) * 128 + k8] =
                *(float4*)&tp[row * TP + k8];
        }
    }
}

// Single MFMA GEMM (no bias): Y16 = Af @ Wp   (for xh0 = h @ cl1_w[0])
__global__ __launch_bounds__(256, 4) void k_gemm0M(
    const float* __restrict__ Af, const __half* __restrict__ Wp,
    __half* __restrict__ Y)
{
    __shared__ __half tls[4][16 * TP];
    const int w = threadIdx.x >> 6;
    const int lane = threadIdx.x & 63;
    const int lm = lane & 15;
    const int lk = lane >> 4;
    const int rbase = blockIdx.x * 64 + w * 16;
    __half* tp = &tls[w][0];
    f32x4 acc[8];
    #pragma unroll
    for (int n = 0; n < 8; ++n) acc[n] = (f32x4){0.f, 0.f, 0.f, 0.f};
    #pragma unroll
    for (int kk = 0; kk < 4; ++kk) {
        const float* ap = &Af[(size_t)(rbase + lm) * 128 + kk * 32 + lk * 8];
        float4 v0 = *(const float4*)ap;
        float4 v1 = *(const float4*)(ap + 4);
        half8 a;
        a[0] = (_Float16)v0.x; a[1] = (_Float16)v0.y;
        a[2] = (_Float16)v0.z; a[3] = (_Float16)v0.w;
        a[4] = (_Float16)v1.x; a[5] = (_Float16)v1.y;
        a[6] = (_Float16)v1.z; a[7] = (_Float16)v1.w;
        #pragma unroll
        for (int n = 0; n < 8; ++n) {
            half8 b = *(const half8*)&Wp[((kk * 8 + n) * 64 + lane) * 8];
            acc[n] = __builtin_amdgcn_mfma_f32_16x16x32_f16(a, b, acc[n], 0, 0, 0);
        }
    }
    #pragma unroll
    for (int n = 0; n < 8; ++n)
        #pragma unroll
        for (int q = 0; q < 4; ++q)
            tp[(lk * 4 + q) * TP + n * 16 + lm] = __float2half_rn(acc[n][q]);
    __syncthreads();
    #pragma unroll
    for (int it = 0; it < 4; ++it) {
        int idx = it * 64 + lane;
        int row = idx >> 4, k8 = (idx & 15) * 8;
        *(float4*)&Y[(size_t)(rbase + row) * 128 + k8] =
            *(float4*)&tp[row * TP + k8];
    }
}

// Partial-sum pooling using sortedness of batch.
__global__ __launch_bounds__(128) void k_pool2(const float* __restrict__ x,
                                               const int* __restrict__ batch,
                                               float* __restrict__ gsum) {
    const int c = threadIdx.x;
    const int n0 = blockIdx.x * 64;
    float acc = 0.f;
    int cur = batch[n0];
    for (int i = 0; i < 64; ++i) {
        int g = batch[n0 + i];
        float v = x[(size_t)(n0 + i) * 128 + c];
        if (g != cur) {
            atomicAdd(&gsum[cur * 128 + c], acc);
            acc = 0.f;
            cur = g;
        }
        acc += v;
    }
    atomicAdd(&gsum[cur * 128 + c], acc);
}

__global__ void k_div(const float* __restrict__ gsum, const int* __restrict__ batch,
                      float* __restrict__ out) {
    int g = blockIdx.x;
    int c = threadIdx.x;
    int a = 0, b = N_NODES;
    while (a < b) { int m = (a + b) >> 1; if (batch[m] < g) a = m + 1; else b = m; }
    int lo = a;
    b = N_NODES;
    while (a < b) { int m = (a + b) >> 1; if (batch[m] < g + 1) a = m + 1; else b = m; }
    int cnt = a - lo;
    out[g * 128 + c] = gsum[g * 128 + c] / fmaxf((float)cnt, 1.0f);
}

extern "C" void kernel_launch(void* const* d_in, const int* in_sizes, int n_in,
                              void* d_out, int out_size, void* d_ws, size_t ws_size,
                              hipStream_t stream) {
    const int*   z       = (const int*)  d_in[0];
    const float* pos     = (const float*)d_in[1];
    const int*   batch   = (const int*)  d_in[2];
    const int*   ei      = (const int*)  d_in[3];
    const float* emb     = (const float*)d_in[4];
    const float* mlp1_w  = (const float*)d_in[5];
    const float* mlp1_b  = (const float*)d_in[6];
    const float* mlp2_w  = (const float*)d_in[7];
    const float* mlp2_b  = (const float*)d_in[8];
    const float* cl1_w   = (const float*)d_in[9];
    const float* cl2_w   = (const float*)d_in[10];
    const float* cl2_b   = (const float*)d_in[11];
    const float* lin_w   = (const float*)d_in[12];
    const float* lin_b   = (const float*)d_in[13];
    const float* out1_w  = (const float*)d_in[14];
    const float* out1_b  = (const float*)d_in[15];
    const float* out2_w  = (const float*)d_in[16];
    const float* out2_b  = (const float*)d_in[17];

    float* ws     = (float*)d_ws;
    float* h      = ws;                               // 2M floats
    float* aggf   = h + (size_t)N_NODES * HID;        // 2M floats (fp32 final / fp16 agg alias)
    __half* agg16 = (__half*)aggf;
    __half* xh16  = (__half*)(aggf + (size_t)N_NODES * HID);  // 2M halves (1M floats)
    float* nxt    = aggf + (size_t)N_NODES * HID + (size_t)N_NODES * HID / 2;
    int2*  meta   = (int2*)nxt;
    int*   cnt    = (int*)(meta + N_EDGES);
    int*   rowptr = cnt + N_NODES;
    int*   wo     = rowptr + N_NODES + 1;
    float* gsum   = (float*)(wo + N_NODES);            // 64*128
    __half* ftab  = (__half*)(gsum + N_GRAPHS * 128);  // NL*TROWS*FILT halves
    __half* wpk   = ftab + (size_t)NL * TROWS * FILT;  // 20*16384 halves

    hipMemsetAsync(cnt, 0, N_NODES * sizeof(int), stream);
    hipMemsetAsync(gsum, 0, N_GRAPHS * 128 * sizeof(float), stream);
    k_embed<<<N_NODES * HID / 256, 256, 0, stream>>>(z, emb, h);
    k_hist<<<N_EDGES / 256, 256, 0, stream>>>(ei, cnt);
    k_scan<<<1, 1024, 0, stream>>>(cnt, rowptr, wo);
    k_scatter<<<N_EDGES / 256, 256, 0, stream>>>(ei, pos, wo, meta);
    k_tab2<<<NL * TROWS / 16, 256, 0, stream>>>(mlp1_w, mlp1_b, mlp2_w, mlp2_b, ftab);
    // fragment-pack weights: [0..5]=cl1, [6..11]=cl2, [12..17]=lin, 18=out1, 19=out2
    k_wpack<<<(6 * 2048 + 255) / 256, 256, 0, stream>>>(cl1_w, wpk, 6);
    k_wpack<<<(6 * 2048 + 255) / 256, 256, 0, stream>>>(cl2_w, wpk + (size_t)6 * 16384, 6);
    k_wpack<<<(6 * 2048 + 255) / 256, 256, 0, stream>>>(lin_w, wpk + (size_t)12 * 16384, 6);
    k_wpack<<<(2048 + 255) / 256, 256, 0, stream>>>(out1_w, wpk + (size_t)18 * 16384, 1);
    k_wpack<<<(2048 + 255) / 256, 256, 0, stream>>>(out2_w, wpk + (size_t)19 * 16384, 1);

    k_gemm0M<<<N_NODES / 64, 256, 0, stream>>>(h, wpk, xh16);
    for (int i = 0; i < NL; ++i) {
        k_edge9<<<N_NODES / 4, 256, 0, stream>>>(
            meta, rowptr, xh16, ftab + (size_t)i * TROWS * FILT, agg16);
        if (i < NL - 1) {
            k_nodeM<false, true, true><<<N_NODES / 64, 256, 0, stream>>>(
                agg16, nullptr,
                wpk + (size_t)(6 + i) * 16384, cl2_b + (size_t)i * HID,
                wpk + (size_t)(12 + i) * 16384, lin_b + (size_t)i * HID,
                h, h, wpk + (size_t)(i + 1) * 16384, xh16);
        } else {
            k_nodeM<false, true, false><<<N_NODES / 64, 256, 0, stream>>>(
                agg16, nullptr,
                wpk + (size_t)(6 + i) * 16384, cl2_b + (size_t)i * HID,
                wpk + (size_t)(12 + i) * 16384, lin_b + (size_t)i * HID,
                h, h, nullptr, nullptr);
        }
    }
    // final MLP: fp32 A (h), output fp32 into aggf; then pool
    k_nodeM<true, false, false><<<N_NODES / 64, 256, 0, stream>>>(
        nullptr, h, wpk + (size_t)18 * 16384, out1_b,
        wpk + (size_t)19 * 16384, out2_b, nullptr, aggf, nullptr, nullptr);
    k_pool2<<<N_NODES / 64, 128, 0, stream>>>(aggf, batch, gsum);
    k_div<<<N_GRAPHS, 128, 0, stream>>>(gsum, batch, (float*)d_out);
}

// Round 23
// 466.081 us; speedup vs baseline: 1.3120x; 1.3120x over previous
//
#include <hip/hip_runtime.h>
#include <hip/hip_fp16.h>
#include <math.h>

#define N_NODES 16384
#define N_EDGES 524288
#define N_GRAPHS 64
#define HID 128
#define FILT 128
#define NG 51
#define NL 6
#define TROWS 2048   // filter-table resolution
#define DMAX 8.66025404f          // 5*sqrt(3), max possible distance
#define DSTEP (DMAX / (TROWS - 1))
#define INV_DSTEP ((TROWS - 1) / DMAX)
#define EU 3         // edge-pair unroll (6 edges in flight)
#define TSTRIDE 132  // fp32 LDS row stride (tab2)
#define TP 136       // fp16 LDS row stride (node MFMA tiles)

typedef _Float16 half8 __attribute__((ext_vector_type(8)));
typedef float f32x4 __attribute__((ext_vector_type(4)));

__device__ __forceinline__ float ssp(float x) {
    float sp = (x > 20.0f) ? x : log1pf(__expf(x));
    return sp - 0.6931471805599453f;
}

__global__ void k_embed(const int* __restrict__ z, const float* __restrict__ emb,
                        float* __restrict__ h) {
    int i = blockIdx.x * blockDim.x + threadIdx.x;
    int n = i >> 7, c = i & 127;
    h[i] = emb[z[n] * HID + c];
}

__global__ void k_hist(const int* __restrict__ ei, int* __restrict__ cnt) {
    int e = blockIdx.x * blockDim.x + threadIdx.x;
    if (e < N_EDGES) atomicAdd(&cnt[ei[e]], 1);
}

__global__ __launch_bounds__(1024) void k_scan(const int* __restrict__ cnt,
                                               int* __restrict__ rowptr,
                                               int* __restrict__ wo) {
    __shared__ int sums[1024];
    int t = threadIdx.x;
    int loc[16];
    int s = 0;
    #pragma unroll
    for (int i = 0; i < 16; ++i) { loc[i] = cnt[t * 16 + i]; s += loc[i]; }
    sums[t] = s;
    __syncthreads();
    for (int off = 1; off < 1024; off <<= 1) {
        int v = sums[t];
        int u = (t >= off) ? sums[t - off] : 0;
        __syncthreads();
        sums[t] = v + u;
        __syncthreads();
    }
    int ex = sums[t] - s;
    #pragma unroll
    for (int i = 0; i < 16; ++i) {
        rowptr[t * 16 + i] = ex;
        wo[t * 16 + i] = ex;
        ex += loc[i];
    }
    if (t == 1023) rowptr[16384] = ex;
}

// scatter into CSR order: meta.x = col, meta.y = ew bits
__global__ void k_scatter(const int* __restrict__ ei, const float* __restrict__ pos,
                          int* __restrict__ wo, int2* __restrict__ meta) {
    int e = blockIdx.x * blockDim.x + threadIdx.x;
    if (e >= N_EDGES) return;
    int r = ei[e], c = ei[N_EDGES + e];
    int p = atomicAdd(&wo[r], 1);
    float dx = pos[r * 3 + 0] - pos[c * 3 + 0];
    float dy = pos[r * 3 + 1] - pos[c * 3 + 1];
    float dz = pos[r * 3 + 2] - pos[c * 3 + 2];
    float ew = sqrtf(dx * dx + dy * dy + dz * dz);
    meta[p] = make_int2(c, __float_as_int(ew));
}

// Pack W[128k][128c] fp32 into MFMA B-fragment order (fp16):
// dst[mat][((kk*8+n)*64+lane)*8 + j] = W[32kk + (lane>>4)*8 + j][16n + (lane&15)]
__global__ void k_wpack(const float* __restrict__ src, __half* __restrict__ dst,
                        int nmat) {
    int idx = blockIdx.x * 256 + threadIdx.x;
    if (idx >= nmat * 2048) return;
    int mat = idx >> 11;
    int r = idx & 2047;
    int kk = r >> 9, n = (r >> 6) & 7, lane = r & 63;
    const float* S = src + (size_t)mat * 16384;
    __half* D = dst + (size_t)mat * 16384 + (size_t)r * 8;
    int k0 = kk * 32 + (lane >> 4) * 8;
    int c = n * 16 + (lane & 15);
    #pragma unroll
    for (int j = 0; j < 8; ++j)
        D[j] = __float2half_rn(S[(k0 + j) * 128 + c]);
}

// Filter tables, wave = 4 rows x 128 channels (lane = channel); fp16 output.
__global__ __launch_bounds__(256, 4) void k_tab2(
    const float* __restrict__ mlp1_w, const float* __restrict__ mlp1_b,
    const float* __restrict__ mlp2_w, const float* __restrict__ mlp2_b,
    __half* __restrict__ ftab)
{
    __shared__ float tls[4 * 4 * TSTRIDE];
    const int w = threadIdx.x >> 6;
    const int lane = threadIdx.x & 63;
    const int gr = blockIdx.x * 16 + w * 4;
    const int layer = gr >> 11;
    const int r0 = gr & (TROWS - 1);
    const float* W1 = mlp1_w + (size_t)layer * NG * FILT;
    const float* B1 = mlp1_b + (size_t)layer * FILT;
    const float* W2 = mlp2_w + (size_t)layer * FILT * FILT;
    const float* B2 = mlp2_b + (size_t)layer * FILT;
    float* tp = &tls[w * 4 * TSTRIDE];
    float acc1[4][2];
    {
        float ba = B1[lane], bb = B1[lane + 64];
        #pragma unroll
        for (int j = 0; j < 4; ++j) { acc1[j][0] = ba; acc1[j][1] = bb; }
    }
    for (int k = 0; k < NG; ++k) {
        float wa = W1[k * FILT + lane];
        float wb = W1[k * FILT + lane + 64];
        #pragma unroll
        for (int j = 0; j < 4; ++j) {
            float dd = (float)(r0 + j) * DSTEP - 0.2f * (float)k;
            float g = __expf(-12.5f * dd * dd);
            acc1[j][0] = fmaf(g, wa, acc1[j][0]);
            acc1[j][1] = fmaf(g, wb, acc1[j][1]);
        }
    }
    #pragma unroll
    for (int j = 0; j < 4; ++j) {
        tp[j * TSTRIDE + lane] = ssp(acc1[j][0]);
        tp[j * TSTRIDE + lane + 64] = ssp(acc1[j][1]);
    }
    __syncthreads();
    float acc2[4][2];
    {
        float ba = B2[lane], bb = B2[lane + 64];
        #pragma unroll
        for (int j = 0; j < 4; ++j) { acc2[j][0] = ba; acc2[j][1] = bb; }
    }
    #pragma unroll 4
    for (int k = 0; k < FILT; k += 2) {
        float w0a = W2[k * FILT + lane];
        float w0b = W2[k * FILT + lane + 64];
        float w1a = W2[(k + 1) * FILT + lane];
        float w1b = W2[(k + 1) * FILT + lane + 64];
        #pragma unroll
        for (int j = 0; j < 4; ++j) {
            float2 t = *(float2*)&tp[j * TSTRIDE + k];
            acc2[j][0] = fmaf(t.x, w0a, fmaf(t.y, w1a, acc2[j][0]));
            acc2[j][1] = fmaf(t.x, w0b, fmaf(t.y, w1b, acc2[j][1]));
        }
    }
    #pragma unroll
    for (int j = 0; j < 4; ++j) {
        float d = (float)(r0 + j) * DSTEP;
        float C = 0.5f * (__cosf(d * 0.31415926535f) + 1.0f);
        __half* out = ftab + (size_t)layer * TROWS * FILT + (size_t)(r0 + j) * FILT;
        out[lane] = __float2half_rn(acc2[j][0] * C);
        out[lane + 64] = __float2half_rn(acc2[j][1] * C);
    }
}

// Half-wave-paired edge aggregation; xh/tab fp16 in, agg fp16 OUT.
__global__ __launch_bounds__(256, 7) void k_edge9(
    const int2* __restrict__ meta, const int* __restrict__ rowptr,
    const __half* __restrict__ xh, const __half* __restrict__ tab,
    __half* __restrict__ agg)
{
    const int row = blockIdx.x * 4 + (threadIdx.x >> 6);
    const int lane = threadIdx.x & 63;
    const int half = lane >> 5;
    const int c4 = (lane & 31) * 4;
    const int es = rowptr[row], ee = rowptr[row + 1];
    float4 acc = make_float4(0.f, 0.f, 0.f, 0.f);
    if (es < ee) {
        int2 mcur[EU];
        #pragma unroll
        for (int u = 0; u < EU; ++u)
            mcur[u] = meta[min(es + 2 * u + half, ee - 1)];
        for (int e = es; e < ee; e += 2 * EU) {
            const int en = e + 2 * EU;
            int2 mnext[EU];
            if (en < ee) {
                #pragma unroll
                for (int u = 0; u < EU; ++u)
                    mnext[u] = meta[min(en + 2 * u + half, ee - 1)];
            }
            float2 t0h[EU], t1h[EU], xr[EU];
            float f[EU], sc[EU];
            #pragma unroll
            for (int u = 0; u < EU; ++u) {
                sc[u] = (e + 2 * u + half < ee) ? 1.f : 0.f;
                float d = __int_as_float(mcur[u].y);
                float uu = d * INV_DSTEP;
                int i0 = min((int)uu, TROWS - 2);
                f[u] = uu - (float)i0;
                t0h[u] = *(const float2*)&tab[(size_t)i0 * FILT + c4];
                t1h[u] = *(const float2*)&tab[(size_t)(i0 + 1) * FILT + c4];
                xr[u]  = *(const float2*)&xh[(size_t)mcur[u].x * FILT + c4];
            }
            #pragma unroll
            for (int u = 0; u < EU; ++u) {
                float2 T0a = __half22float2(*reinterpret_cast<__half2*>(&t0h[u].x));
                float2 T0b = __half22float2(*reinterpret_cast<__half2*>(&t0h[u].y));
                float2 T1a = __half22float2(*reinterpret_cast<__half2*>(&t1h[u].x));
                float2 T1b = __half22float2(*reinterpret_cast<__half2*>(&t1h[u].y));
                float2 x01 = __half22float2(*reinterpret_cast<__half2*>(&xr[u].x));
                float2 x23 = __half22float2(*reinterpret_cast<__half2*>(&xr[u].y));
                acc.x = fmaf(fmaf(f[u], T1a.x - T0a.x, T0a.x) * sc[u], x01.x, acc.x);
                acc.y = fmaf(fmaf(f[u], T1a.y - T0a.y, T0a.y) * sc[u], x01.y, acc.y);
                acc.z = fmaf(fmaf(f[u], T1b.x - T0b.x, T0b.x) * sc[u], x23.x, acc.z);
                acc.w = fmaf(fmaf(f[u], T1b.y - T0b.y, T0b.y) * sc[u], x23.y, acc.w);
            }
            #pragma unroll
            for (int u = 0; u < EU; ++u) mcur[u] = mnext[u];
        }
        acc.x += __shfl_xor(acc.x, 32, 64);
        acc.y += __shfl_xor(acc.y, 32, 64);
        acc.z += __shfl_xor(acc.z, 32, 64);
        acc.w += __shfl_xor(acc.w, 32, 64);
    }
    if (half == 0) {
        float2 st;
        ((__half2*)&st)[0] = __floats2half2_rn(acc.x, acc.y);
        ((__half2*)&st)[1] = __floats2half2_rn(acc.z, acc.w);
        *(float2*)&agg[(size_t)row * FILT + c4] = st;
    }
}

// ---------------------------------------------------------------------------
// MFMA node GEMMs v2: block = 16 nodes, 4 waves; wave owns 2 N-tiles
// (16 nodes x 32 ch). Grid = 1024 -> 4 blocks/CU, 16 waves/CU. Block-shared
// fp16 activation tile [16][TP] between GEMMs. Fragment layouts identical to
// the R22-verified kernel.
// ---------------------------------------------------------------------------
template<bool A32, bool RESID, bool G3>
__global__ __launch_bounds__(256, 8) void k_nodeM2(
    const __half* __restrict__ Ah, const float* __restrict__ Af,
    const __half* __restrict__ Wp1, const float* __restrict__ B1,
    const __half* __restrict__ Wp2, const float* __restrict__ B2,
    const float* __restrict__ Hin, float* __restrict__ Hout,
    const __half* __restrict__ Wp3, __half* __restrict__ XHout)
{
    __shared__ __half tp[16 * TP];   // 4352 B
    const int w = threadIdx.x >> 6;
    const int lane = threadIdx.x & 63;
    const int lm = lane & 15;
    const int lk = lane >> 4;
    const int rbase = blockIdx.x * 16;
    const int n0 = w * 2;

    // ---- GEMM1 ----
    f32x4 acc[2];
    #pragma unroll
    for (int t = 0; t < 2; ++t) acc[t] = (f32x4){0.f, 0.f, 0.f, 0.f};
    #pragma unroll
    for (int kk = 0; kk < 4; ++kk) {
        half8 a;
        if (A32) {
            const float* ap = &Af[(size_t)(rbase + lm) * 128 + kk * 32 + lk * 8];
            float4 v0 = *(const float4*)ap;
            float4 v1 = *(const float4*)(ap + 4);
            a[0] = (_Float16)v0.x; a[1] = (_Float16)v0.y;
            a[2] = (_Float16)v0.z; a[3] = (_Float16)v0.w;
            a[4] = (_Float16)v1.x; a[5] = (_Float16)v1.y;
            a[6] = (_Float16)v1.z; a[7] = (_Float16)v1.w;
        } else {
            a = *(const half8*)&Ah[(size_t)(rbase + lm) * 128 + kk * 32 + lk * 8];
        }
        #pragma unroll
        for (int t = 0; t < 2; ++t) {
            half8 b = *(const half8*)&Wp1[((kk * 8 + n0 + t) * 64 + lane) * 8];
            acc[t] = __builtin_amdgcn_mfma_f32_16x16x32_f16(a, b, acc[t], 0, 0, 0);
        }
    }
    #pragma unroll
    for (int t = 0; t < 2; ++t) {
        int n = n0 + t;
        float bv = B1[n * 16 + lm];
        #pragma unroll
        for (int q = 0; q < 4; ++q)
            tp[(lk * 4 + q) * TP + n * 16 + lm] = __float2half_rn(ssp(acc[t][q] + bv));
    }
    __syncthreads();
    // ---- GEMM2 ----
    f32x4 acc2[2];
    #pragma unroll
    for (int t = 0; t < 2; ++t) acc2[t] = (f32x4){0.f, 0.f, 0.f, 0.f};
    #pragma unroll
    for (int kk = 0; kk < 4; ++kk) {
        half8 a = *(const half8*)&tp[lm * TP + kk * 32 + lk * 8];
        #pragma unroll
        for (int t = 0; t < 2; ++t) {
            half8 b = *(const half8*)&Wp2[((kk * 8 + n0 + t) * 64 + lane) * 8];
            acc2[t] = __builtin_amdgcn_mfma_f32_16x16x32_f16(a, b, acc2[t], 0, 0, 0);
        }
    }
    __syncthreads();   // all tp reads done before overwrite
    #pragma unroll
    for (int t = 0; t < 2; ++t) {
        int n = n0 + t;
        float bv = B2[n * 16 + lm];
        #pragma unroll
        for (int q = 0; q < 4; ++q) {
            size_t ro = (size_t)(rbase + lk * 4 + q) * 128 + n * 16 + lm;
            float v = acc2[t][q] + bv;
            if (RESID) v += Hin[ro];
            Hout[ro] = v;
            if (G3) tp[(lk * 4 + q) * TP + n * 16 + lm] = __float2half_rn(v);
        }
    }
    if (G3) {
        __syncthreads();
        f32x4 acc3[2];
        #pragma unroll
        for (int t = 0; t < 2; ++t) acc3[t] = (f32x4){0.f, 0.f, 0.f, 0.f};
        #pragma unroll
        for (int kk = 0; kk < 4; ++kk) {
            half8 a = *(const half8*)&tp[lm * TP + kk * 32 + lk * 8];
            #pragma unroll
            for (int t = 0; t < 2; ++t) {
                half8 b = *(const half8*)&Wp3[((kk * 8 + n0 + t) * 64 + lane) * 8];
                acc3[t] = __builtin_amdgcn_mfma_f32_16x16x32_f16(a, b, acc3[t], 0, 0, 0);
            }
        }
        __syncthreads();
        #pragma unroll
        for (int t = 0; t < 2; ++t) {
            int n = n0 + t;
            #pragma unroll
            for (int q = 0; q < 4; ++q)
                tp[(lk * 4 + q) * TP + n * 16 + lm] = __float2half_rn(acc3[t][q]);
        }
        __syncthreads();
        // coalesced fp16 writeback of the block's 16x128 tile (256 thr x 16B)
        int idx = threadIdx.x;
        int row = idx >> 4, k8 = (idx & 15) * 8;
        *(float4*)&XHout[(size_t)(rbase + row) * 128 + k8] =
            *(float4*)&tp[row * TP + k8];
    }
}

// Single MFMA GEMM (no bias): Y16 = Af @ Wp   (xh0 = h @ cl1_w[0])
__global__ __launch_bounds__(256, 8) void k_gemm0M2(
    const float* __restrict__ Af, const __half* __restrict__ Wp,
    __half* __restrict__ Y)
{
    __shared__ __half tp[16 * TP];
    const int w = threadIdx.x >> 6;
    const int lane = threadIdx.x & 63;
    const int lm = lane & 15;
    const int lk = lane >> 4;
    const int rbase = blockIdx.x * 16;
    const int n0 = w * 2;
    f32x4 acc[2];
    #pragma unroll
    for (int t = 0; t < 2; ++t) acc[t] = (f32x4){0.f, 0.f, 0.f, 0.f};
    #pragma unroll
    for (int kk = 0; kk < 4; ++kk) {
        const float* ap = &Af[(size_t)(rbase + lm) * 128 + kk * 32 + lk * 8];
        float4 v0 = *(const float4*)ap;
        float4 v1 = *(const float4*)(ap + 4);
        half8 a;
        a[0] = (_Float16)v0.x; a[1] = (_Float16)v0.y;
        a[2] = (_Float16)v0.z; a[3] = (_Float16)v0.w;
        a[4] = (_Float16)v1.x; a[5] = (_Float16)v1.y;
        a[6] = (_Float16)v1.z; a[7] = (_Float16)v1.w;
        #pragma unroll
        for (int t = 0; t < 2; ++t) {
            half8 b = *(const half8*)&Wp[((kk * 8 + n0 + t) * 64 + lane) * 8];
            acc[t] = __builtin_amdgcn_mfma_f32_16x16x32_f16(a, b, acc[t], 0, 0, 0);
        }
    }
    #pragma unroll
    for (int t = 0; t < 2; ++t) {
        int n = n0 + t;
        #pragma unroll
        for (int q = 0; q < 4; ++q)
            tp[(lk * 4 + q) * TP + n * 16 + lm] = __float2half_rn(acc[t][q]);
    }
    __syncthreads();
    int idx = threadIdx.x;
    int row = idx >> 4, k8 = (idx & 15) * 8;
    *(float4*)&Y[(size_t)(rbase + row) * 128 + k8] = *(float4*)&tp[row * TP + k8];
}

// Partial-sum pooling using sortedness of batch.
__global__ __launch_bounds__(128) void k_pool2(const float* __restrict__ x,
                                               const int* __restrict__ batch,
                                               float* __restrict__ gsum) {
    const int c = threadIdx.x;
    const int n0 = blockIdx.x * 64;
    float acc = 0.f;
    int cur = batch[n0];
    for (int i = 0; i < 64; ++i) {
        int g = batch[n0 + i];
        float v = x[(size_t)(n0 + i) * 128 + c];
        if (g != cur) {
            atomicAdd(&gsum[cur * 128 + c], acc);
            acc = 0.f;
            cur = g;
        }
        acc += v;
    }
    atomicAdd(&gsum[cur * 128 + c], acc);
}

__global__ void k_div(const float* __restrict__ gsum, const int* __restrict__ batch,
                      float* __restrict__ out) {
    int g = blockIdx.x;
    int c = threadIdx.x;
    int a = 0, b = N_NODES;
    while (a < b) { int m = (a + b) >> 1; if (batch[m] < g) a = m + 1; else b = m; }
    int lo = a;
    b = N_NODES;
    while (a < b) { int m = (a + b) >> 1; if (batch[m] < g + 1) a = m + 1; else b = m; }
    int cnt = a - lo;
    out[g * 128 + c] = gsum[g * 128 + c] / fmaxf((float)cnt, 1.0f);
}

extern "C" void kernel_launch(void* const* d_in, const int* in_sizes, int n_in,
                              void* d_out, int out_size, void* d_ws, size_t ws_size,
                              hipStream_t stream) {
    const int*   z       = (const int*)  d_in[0];
    const float* pos     = (const float*)d_in[1];
    const int*   batch   = (const int*)  d_in[2];
    const int*   ei      = (const int*)  d_in[3];
    const float* emb     = (const float*)d_in[4];
    const float* mlp1_w  = (const float*)d_in[5];
    const float* mlp1_b  = (const float*)d_in[6];
    const float* mlp2_w  = (const float*)d_in[7];
    const float* mlp2_b  = (const float*)d_in[8];
    const float* cl1_w   = (const float*)d_in[9];
    const float* cl2_w   = (const float*)d_in[10];
    const float* cl2_b   = (const float*)d_in[11];
    const float* lin_w   = (const float*)d_in[12];
    const float* lin_b   = (const float*)d_in[13];
    const float* out1_w  = (const float*)d_in[14];
    const float* out1_b  = (const float*)d_in[15];
    const float* out2_w  = (const float*)d_in[16];
    const float* out2_b  = (const float*)d_in[17];

    float* ws     = (float*)d_ws;
    float* h      = ws;                               // 2M floats
    float* aggf   = h + (size_t)N_NODES * HID;        // 2M floats (fp32 final / fp16 agg alias)
    __half* agg16 = (__half*)aggf;
    __half* xh16  = (__half*)(aggf + (size_t)N_NODES * HID);  // 2M halves (1M floats)
    float* nxt    = aggf + (size_t)N_NODES * HID + (size_t)N_NODES * HID / 2;
    int2*  meta   = (int2*)nxt;
    int*   cnt    = (int*)(meta + N_EDGES);
    int*   rowptr = cnt + N_NODES;
    int*   wo     = rowptr + N_NODES + 1;
    float* gsum   = (float*)(wo + N_NODES);            // 64*128
    __half* ftab  = (__half*)(gsum + N_GRAPHS * 128);  // NL*TROWS*FILT halves
    __half* wpk   = ftab + (size_t)NL * TROWS * FILT;  // 20*16384 halves

    hipMemsetAsync(cnt, 0, N_NODES * sizeof(int), stream);
    hipMemsetAsync(gsum, 0, N_GRAPHS * 128 * sizeof(float), stream);
    k_embed<<<N_NODES * HID / 256, 256, 0, stream>>>(z, emb, h);
    k_hist<<<N_EDGES / 256, 256, 0, stream>>>(ei, cnt);
    k_scan<<<1, 1024, 0, stream>>>(cnt, rowptr, wo);
    k_scatter<<<N_EDGES / 256, 256, 0, stream>>>(ei, pos, wo, meta);
    k_tab2<<<NL * TROWS / 16, 256, 0, stream>>>(mlp1_w, mlp1_b, mlp2_w, mlp2_b, ftab);
    // fragment-pack weights: [0..5]=cl1, [6..11]=cl2, [12..17]=lin, 18=out1, 19=out2
    k_wpack<<<(6 * 2048 + 255) / 256, 256, 0, stream>>>(cl1_w, wpk, 6);
    k_wpack<<<(6 * 2048 + 255) / 256, 256, 0, stream>>>(cl2_w, wpk + (size_t)6 * 16384, 6);
    k_wpack<<<(6 * 2048 + 255) / 256, 256, 0, stream>>>(lin_w, wpk + (size_t)12 * 16384, 6);
    k_wpack<<<(2048 + 255) / 256, 256, 0, stream>>>(out1_w, wpk + (size_t)18 * 16384, 1);
    k_wpack<<<(2048 + 255) / 256, 256, 0, stream>>>(out2_w, wpk + (size_t)19 * 16384, 1);

    k_gemm0M2<<<N_NODES / 16, 256, 0, stream>>>(h, wpk, xh16);
    for (int i = 0; i < NL; ++i) {
        k_edge9<<<N_NODES / 4, 256, 0, stream>>>(
            meta, rowptr, xh16, ftab + (size_t)i * TROWS * FILT, agg16);
        if (i < NL - 1) {
            k_nodeM2<false, true, true><<<N_NODES / 16, 256, 0, stream>>>(
                agg16, nullptr,
                wpk + (size_t)(6 + i) * 16384, cl2_b + (size_t)i * HID,
                wpk + (size_t)(12 + i) * 16384, lin_b + (size_t)i * HID,
                h, h, wpk + (size_t)(i + 1) * 16384, xh16);
        } else {
            k_nodeM2<false, true, false><<<N_NODES / 16, 256, 0, stream>>>(
                agg16, nullptr,
                wpk + (size_t)(6 + i) * 16384, cl2_b + (size_t)i * HID,
                wpk + (size_t)(12 + i) * 16384, lin_b + (size_t)i * HID,
                h, h, nullptr, nullptr);
        }
    }
    // final MLP: fp32 A (h), output fp32 into aggf; then pool
    k_nodeM2<true, false, false><<<N_NODES / 16, 256, 0, stream>>>(
        nullptr, h, wpk + (size_t)18 * 16384, out1_b,
        wpk + (size_t)19 * 16384, out2_b, nullptr, aggf, nullptr, nullptr);
    k_pool2<<<N_NODES / 64, 128, 0, stream>>>(aggf, batch, gsum);
    k_div<<<N_GRAPHS, 128, 0, stream>>>(gsum, batch, (float*)d_out);
}

// Round 24
// 398.540 us; speedup vs baseline: 1.5343x; 1.1695x over previous
//
#include <hip/hip_runtime.h>
#include <hip/hip_fp16.h>
#include <math.h>

#define N_NODES 16384
#define N_EDGES 524288
#define N_GRAPHS 64
#define HID 128
#define FILT 128
#define NG 51
#define NL 6
#define TROWS 2048   // filter-table resolution
#define DMAX 8.66025404f          // 5*sqrt(3), max possible distance
#define DSTEP (DMAX / (TROWS - 1))
#define INV_DSTEP ((TROWS - 1) / DMAX)
#define EU2 2        // edge-quad unroll (8 edges in flight)
#define TSTRIDE 132  // fp32 LDS row stride (tab2)
#define TP 136       // fp16 LDS row stride (node MFMA tiles)

typedef _Float16 half8 __attribute__((ext_vector_type(8)));
typedef float f32x4 __attribute__((ext_vector_type(4)));

__device__ __forceinline__ float ssp(float x) {
    float sp = (x > 20.0f) ? x : log1pf(__expf(x));
    return sp - 0.6931471805599453f;
}

__global__ void k_embed(const int* __restrict__ z, const float* __restrict__ emb,
                        float* __restrict__ h) {
    int i = blockIdx.x * blockDim.x + threadIdx.x;
    int n = i >> 7, c = i & 127;
    h[i] = emb[z[n] * HID + c];
}

__global__ void k_hist(const int* __restrict__ ei, int* __restrict__ cnt) {
    int e = blockIdx.x * blockDim.x + threadIdx.x;
    if (e < N_EDGES) atomicAdd(&cnt[ei[e]], 1);
}

__global__ __launch_bounds__(1024) void k_scan(const int* __restrict__ cnt,
                                               int* __restrict__ rowptr,
                                               int* __restrict__ wo) {
    __shared__ int sums[1024];
    int t = threadIdx.x;
    int loc[16];
    int s = 0;
    #pragma unroll
    for (int i = 0; i < 16; ++i) { loc[i] = cnt[t * 16 + i]; s += loc[i]; }
    sums[t] = s;
    __syncthreads();
    for (int off = 1; off < 1024; off <<= 1) {
        int v = sums[t];
        int u = (t >= off) ? sums[t - off] : 0;
        __syncthreads();
        sums[t] = v + u;
        __syncthreads();
    }
    int ex = sums[t] - s;
    #pragma unroll
    for (int i = 0; i < 16; ++i) {
        rowptr[t * 16 + i] = ex;
        wo[t * 16 + i] = ex;
        ex += loc[i];
    }
    if (t == 1023) rowptr[16384] = ex;
}

// scatter into CSR order: meta.x = col, meta.y = ew bits
__global__ void k_scatter(const int* __restrict__ ei, const float* __restrict__ pos,
                          int* __restrict__ wo, int2* __restrict__ meta) {
    int e = blockIdx.x * blockDim.x + threadIdx.x;
    if (e >= N_EDGES) return;
    int r = ei[e], c = ei[N_EDGES + e];
    int p = atomicAdd(&wo[r], 1);
    float dx = pos[r * 3 + 0] - pos[c * 3 + 0];
    float dy = pos[r * 3 + 1] - pos[c * 3 + 1];
    float dz = pos[r * 3 + 2] - pos[c * 3 + 2];
    float ew = sqrtf(dx * dx + dy * dy + dz * dz);
    meta[p] = make_int2(c, __float_as_int(ew));
}

// Pack W[128k][128c] fp32 into MFMA B-fragment order (fp16)
__global__ void k_wpack(const float* __restrict__ src, __half* __restrict__ dst,
                        int nmat) {
    int idx = blockIdx.x * 256 + threadIdx.x;
    if (idx >= nmat * 2048) return;
    int mat = idx >> 11;
    int r = idx & 2047;
    int kk = r >> 9, n = (r >> 6) & 7, lane = r & 63;
    const float* S = src + (size_t)mat * 16384;
    __half* D = dst + (size_t)mat * 16384 + (size_t)r * 8;
    int k0 = kk * 32 + (lane >> 4) * 8;
    int c = n * 16 + (lane & 15);
    #pragma unroll
    for (int j = 0; j < 8; ++j)
        D[j] = __float2half_rn(S[(k0 + j) * 128 + c]);
}

// Filter tables, wave = 4 rows x 128 channels (lane = channel); fp16 output.
__global__ __launch_bounds__(256, 4) void k_tab2(
    const float* __restrict__ mlp1_w, const float* __restrict__ mlp1_b,
    const float* __restrict__ mlp2_w, const float* __restrict__ mlp2_b,
    __half* __restrict__ ftab)
{
    __shared__ float tls[4 * 4 * TSTRIDE];
    const int w = threadIdx.x >> 6;
    const int lane = threadIdx.x & 63;
    const int gr = blockIdx.x * 16 + w * 4;
    const int layer = gr >> 11;
    const int r0 = gr & (TROWS - 1);
    const float* W1 = mlp1_w + (size_t)layer * NG * FILT;
    const float* B1 = mlp1_b + (size_t)layer * FILT;
    const float* W2 = mlp2_w + (size_t)layer * FILT * FILT;
    const float* B2 = mlp2_b + (size_t)layer * FILT;
    float* tp = &tls[w * 4 * TSTRIDE];
    float acc1[4][2];
    {
        float ba = B1[lane], bb = B1[lane + 64];
        #pragma unroll
        for (int j = 0; j < 4; ++j) { acc1[j][0] = ba; acc1[j][1] = bb; }
    }
    for (int k = 0; k < NG; ++k) {
        float wa = W1[k * FILT + lane];
        float wb = W1[k * FILT + lane + 64];
        #pragma unroll
        for (int j = 0; j < 4; ++j) {
            float dd = (float)(r0 + j) * DSTEP - 0.2f * (float)k;
            float g = __expf(-12.5f * dd * dd);
            acc1[j][0] = fmaf(g, wa, acc1[j][0]);
            acc1[j][1] = fmaf(g, wb, acc1[j][1]);
        }
    }
    #pragma unroll
    for (int j = 0; j < 4; ++j) {
        tp[j * TSTRIDE + lane] = ssp(acc1[j][0]);
        tp[j * TSTRIDE + lane + 64] = ssp(acc1[j][1]);
    }
    __syncthreads();
    float acc2[4][2];
    {
        float ba = B2[lane], bb = B2[lane + 64];
        #pragma unroll
        for (int j = 0; j < 4; ++j) { acc2[j][0] = ba; acc2[j][1] = bb; }
    }
    #pragma unroll 4
    for (int k = 0; k < FILT; k += 2) {
        float w0a = W2[k * FILT + lane];
        float w0b = W2[k * FILT + lane + 64];
        float w1a = W2[(k + 1) * FILT + lane];
        float w1b = W2[(k + 1) * FILT + lane + 64];
        #pragma unroll
        for (int j = 0; j < 4; ++j) {
            float2 t = *(float2*)&tp[j * TSTRIDE + k];
            acc2[j][0] = fmaf(t.x, w0a, fmaf(t.y, w1a, acc2[j][0]));
            acc2[j][1] = fmaf(t.x, w0b, fmaf(t.y, w1b, acc2[j][1]));
        }
    }
    #pragma unroll
    for (int j = 0; j < 4; ++j) {
        float d = (float)(r0 + j) * DSTEP;
        float C = 0.5f * (__cosf(d * 0.31415926535f) + 1.0f);
        __half* out = ftab + (size_t)layer * TROWS * FILT + (size_t)(r0 + j) * FILT;
        out[lane] = __float2half_rn(acc2[j][0] * C);
        out[lane + 64] = __float2half_rn(acc2[j][1] * C);
    }
}

// Quarter-wave edge aggregation: 16 lanes x 8 ch per edge (one half8 load per
// operand), wave processes 4 edges concurrently; packed fp16 lerp, fp32 acc
// via mixed-precision fma. agg fp16 out.
__global__ __launch_bounds__(256, 7) void k_edge10(
    const int2* __restrict__ meta, const int* __restrict__ rowptr,
    const __half* __restrict__ xh, const __half* __restrict__ tab,
    __half* __restrict__ agg)
{
    const int row = blockIdx.x * 4 + (threadIdx.x >> 6);
    const int lane = threadIdx.x & 63;
    const int q = lane >> 4;          // quarter 0..3 -> edge e+q
    const int ch8 = (lane & 15) * 8;  // 8 channels per lane
    const int es = rowptr[row], ee = rowptr[row + 1];
    float acc[8];
    #pragma unroll
    for (int j = 0; j < 8; ++j) acc[j] = 0.f;
    if (es < ee) {
        for (int e = es; e < ee; e += 4 * EU2) {
            int2 m[EU2];
            #pragma unroll
            for (int u = 0; u < EU2; ++u)
                m[u] = meta[min(e + 4 * u + q, ee - 1)];
            half8 t0[EU2], t1[EU2], xv[EU2];
            float f[EU2], sc[EU2];
            #pragma unroll
            for (int u = 0; u < EU2; ++u) {
                sc[u] = (e + 4 * u + q < ee) ? 1.f : 0.f;
                float d = __int_as_float(m[u].y);
                float uu = d * INV_DSTEP;
                int i0 = min((int)uu, TROWS - 2);
                f[u] = uu - (float)i0;
                t0[u] = *(const half8*)&tab[(size_t)i0 * FILT + ch8];
                t1[u] = *(const half8*)&tab[(size_t)(i0 + 1) * FILT + ch8];
                xv[u] = *(const half8*)&xh[(size_t)m[u].x * FILT + ch8];
            }
            #pragma unroll
            for (int u = 0; u < EU2; ++u) {
                _Float16 fh = (_Float16)f[u];
                _Float16 sh = (_Float16)sc[u];
                #pragma unroll
                for (int j = 0; j < 8; ++j) {
                    _Float16 w = (_Float16)((t0[u][j] + fh * (t1[u][j] - t0[u][j])) * sh);
                    acc[j] += (float)w * (float)xv[u][j];
                }
            }
        }
        #pragma unroll
        for (int j = 0; j < 8; ++j) {
            acc[j] += __shfl_xor(acc[j], 16, 64);
            acc[j] += __shfl_xor(acc[j], 32, 64);
        }
    }
    if (q == 0) {
        float4 v;
        ((__half2*)&v)[0] = __floats2half2_rn(acc[0], acc[1]);
        ((__half2*)&v)[1] = __floats2half2_rn(acc[2], acc[3]);
        ((__half2*)&v)[2] = __floats2half2_rn(acc[4], acc[5]);
        ((__half2*)&v)[3] = __floats2half2_rn(acc[6], acc[7]);
        *(float4*)&agg[(size_t)row * FILT + ch8] = v;
    }
}

// ---------------------------------------------------------------------------
// MFMA node GEMMs v2 (R23-verified): block = 16 nodes, 4 waves; wave owns
// 2 N-tiles. Grid = 1024 -> 16 waves/CU.
// ---------------------------------------------------------------------------
template<bool A32, bool RESID, bool G3>
__global__ __launch_bounds__(256, 8) void k_nodeM2(
    const __half* __restrict__ Ah, const float* __restrict__ Af,
    const __half* __restrict__ Wp1, const float* __restrict__ B1,
    const __half* __restrict__ Wp2, const float* __restrict__ B2,
    const float* __restrict__ Hin, float* __restrict__ Hout,
    const __half* __restrict__ Wp3, __half* __restrict__ XHout)
{
    __shared__ __half tp[16 * TP];   // 4352 B
    const int w = threadIdx.x >> 6;
    const int lane = threadIdx.x & 63;
    const int lm = lane & 15;
    const int lk = lane >> 4;
    const int rbase = blockIdx.x * 16;
    const int n0 = w * 2;

    // ---- GEMM1 ----
    f32x4 acc[2];
    #pragma unroll
    for (int t = 0; t < 2; ++t) acc[t] = (f32x4){0.f, 0.f, 0.f, 0.f};
    #pragma unroll
    for (int kk = 0; kk < 4; ++kk) {
        half8 a;
        if (A32) {
            const float* ap = &Af[(size_t)(rbase + lm) * 128 + kk * 32 + lk * 8];
            float4 v0 = *(const float4*)ap;
            float4 v1 = *(const float4*)(ap + 4);
            a[0] = (_Float16)v0.x; a[1] = (_Float16)v0.y;
            a[2] = (_Float16)v0.z; a[3] = (_Float16)v0.w;
            a[4] = (_Float16)v1.x; a[5] = (_Float16)v1.y;
            a[6] = (_Float16)v1.z; a[7] = (_Float16)v1.w;
        } else {
            a = *(const half8*)&Ah[(size_t)(rbase + lm) * 128 + kk * 32 + lk * 8];
        }
        #pragma unroll
        for (int t = 0; t < 2; ++t) {
            half8 b = *(const half8*)&Wp1[((kk * 8 + n0 + t) * 64 + lane) * 8];
            acc[t] = __builtin_amdgcn_mfma_f32_16x16x32_f16(a, b, acc[t], 0, 0, 0);
        }
    }
    #pragma unroll
    for (int t = 0; t < 2; ++t) {
        int n = n0 + t;
        float bv = B1[n * 16 + lm];
        #pragma unroll
        for (int q = 0; q < 4; ++q)
            tp[(lk * 4 + q) * TP + n * 16 + lm] = __float2half_rn(ssp(acc[t][q] + bv));
    }
    __syncthreads();
    // ---- GEMM2 ----
    f32x4 acc2[2];
    #pragma unroll
    for (int t = 0; t < 2; ++t) acc2[t] = (f32x4){0.f, 0.f, 0.f, 0.f};
    #pragma unroll
    for (int kk = 0; kk < 4; ++kk) {
        half8 a = *(const half8*)&tp[lm * TP + kk * 32 + lk * 8];
        #pragma unroll
        for (int t = 0; t < 2; ++t) {
            half8 b = *(const half8*)&Wp2[((kk * 8 + n0 + t) * 64 + lane) * 8];
            acc2[t] = __builtin_amdgcn_mfma_f32_16x16x32_f16(a, b, acc2[t], 0, 0, 0);
        }
    }
    __syncthreads();
    #pragma unroll
    for (int t = 0; t < 2; ++t) {
        int n = n0 + t;
        float bv = B2[n * 16 + lm];
        #pragma unroll
        for (int q = 0; q < 4; ++q) {
            size_t ro = (size_t)(rbase + lk * 4 + q) * 128 + n * 16 + lm;
            float v = acc2[t][q] + bv;
            if (RESID) v += Hin[ro];
            Hout[ro] = v;
            if (G3) tp[(lk * 4 + q) * TP + n * 16 + lm] = __float2half_rn(v);
        }
    }
    if (G3) {
        __syncthreads();
        f32x4 acc3[2];
        #pragma unroll
        for (int t = 0; t < 2; ++t) acc3[t] = (f32x4){0.f, 0.f, 0.f, 0.f};
        #pragma unroll
        for (int kk = 0; kk < 4; ++kk) {
            half8 a = *(const half8*)&tp[lm * TP + kk * 32 + lk * 8];
            #pragma unroll
            for (int t = 0; t < 2; ++t) {
                half8 b = *(const half8*)&Wp3[((kk * 8 + n0 + t) * 64 + lane) * 8];
                acc3[t] = __builtin_amdgcn_mfma_f32_16x16x32_f16(a, b, acc3[t], 0, 0, 0);
            }
        }
        __syncthreads();
        #pragma unroll
        for (int t = 0; t < 2; ++t) {
            int n = n0 + t;
            #pragma unroll
            for (int q = 0; q < 4; ++q)
                tp[(lk * 4 + q) * TP + n * 16 + lm] = __float2half_rn(acc3[t][q]);
        }
        __syncthreads();
        int idx = threadIdx.x;
        int r2 = idx >> 4, k8 = (idx & 15) * 8;
        *(float4*)&XHout[(size_t)(rbase + r2) * 128 + k8] =
            *(float4*)&tp[r2 * TP + k8];
    }
}

// Single MFMA GEMM (no bias): Y16 = Af @ Wp   (xh0 = h @ cl1_w[0])
__global__ __launch_bounds__(256, 8) void k_gemm0M2(
    const float* __restrict__ Af, const __half* __restrict__ Wp,
    __half* __restrict__ Y)
{
    __shared__ __half tp[16 * TP];
    const int w = threadIdx.x >> 6;
    const int lane = threadIdx.x & 63;
    const int lm = lane & 15;
    const int lk = lane >> 4;
    const int rbase = blockIdx.x * 16;
    const int n0 = w * 2;
    f32x4 acc[2];
    #pragma unroll
    for (int t = 0; t < 2; ++t) acc[t] = (f32x4){0.f, 0.f, 0.f, 0.f};
    #pragma unroll
    for (int kk = 0; kk < 4; ++kk) {
        const float* ap = &Af[(size_t)(rbase + lm) * 128 + kk * 32 + lk * 8];
        float4 v0 = *(const float4*)ap;
        float4 v1 = *(const float4*)(ap + 4);
        half8 a;
        a[0] = (_Float16)v0.x; a[1] = (_Float16)v0.y;
        a[2] = (_Float16)v0.z; a[3] = (_Float16)v0.w;
        a[4] = (_Float16)v1.x; a[5] = (_Float16)v1.y;
        a[6] = (_Float16)v1.z; a[7] = (_Float16)v1.w;
        #pragma unroll
        for (int t = 0; t < 2; ++t) {
            half8 b = *(const half8*)&Wp[((kk * 8 + n0 + t) * 64 + lane) * 8];
            acc[t] = __builtin_amdgcn_mfma_f32_16x16x32_f16(a, b, acc[t], 0, 0, 0);
        }
    }
    #pragma unroll
    for (int t = 0; t < 2; ++t) {
        int n = n0 + t;
        #pragma unroll
        for (int q = 0; q < 4; ++q)
            tp[(lk * 4 + q) * TP + n * 16 + lm] = __float2half_rn(acc[t][q]);
    }
    __syncthreads();
    int idx = threadIdx.x;
    int r2 = idx >> 4, k8 = (idx & 15) * 8;
    *(float4*)&Y[(size_t)(rbase + r2) * 128 + k8] = *(float4*)&tp[r2 * TP + k8];
}

// Partial-sum pooling using sortedness of batch.
__global__ __launch_bounds__(128) void k_pool2(const float* __restrict__ x,
                                               const int* __restrict__ batch,
                                               float* __restrict__ gsum) {
    const int c = threadIdx.x;
    const int n0 = blockIdx.x * 64;
    float acc = 0.f;
    int cur = batch[n0];
    for (int i = 0; i < 64; ++i) {
        int g = batch[n0 + i];
        float v = x[(size_t)(n0 + i) * 128 + c];
        if (g != cur) {
            atomicAdd(&gsum[cur * 128 + c], acc);
            acc = 0.f;
            cur = g;
        }
        acc += v;
    }
    atomicAdd(&gsum[cur * 128 + c], acc);
}

__global__ void k_div(const float* __restrict__ gsum, const int* __restrict__ batch,
                      float* __restrict__ out) {
    int g = blockIdx.x;
    int c = threadIdx.x;
    int a = 0, b = N_NODES;
    while (a < b) { int m = (a + b) >> 1; if (batch[m] < g) a = m + 1; else b = m; }
    int lo = a;
    b = N_NODES;
    while (a < b) { int m = (a + b) >> 1; if (batch[m] < g + 1) a = m + 1; else b = m; }
    int cnt = a - lo;
    out[g * 128 + c] = gsum[g * 128 + c] / fmaxf((float)cnt, 1.0f);
}

extern "C" void kernel_launch(void* const* d_in, const int* in_sizes, int n_in,
                              void* d_out, int out_size, void* d_ws, size_t ws_size,
                              hipStream_t stream) {
    const int*   z       = (const int*)  d_in[0];
    const float* pos     = (const float*)d_in[1];
    const int*   batch   = (const int*)  d_in[2];
    const int*   ei      = (const int*)  d_in[3];
    const float* emb     = (const float*)d_in[4];
    const float* mlp1_w  = (const float*)d_in[5];
    const float* mlp1_b  = (const float*)d_in[6];
    const float* mlp2_w  = (const float*)d_in[7];
    const float* mlp2_b  = (const float*)d_in[8];
    const float* cl1_w   = (const float*)d_in[9];
    const float* cl2_w   = (const float*)d_in[10];
    const float* cl2_b   = (const float*)d_in[11];
    const float* lin_w   = (const float*)d_in[12];
    const float* lin_b   = (const float*)d_in[13];
    const float* out1_w  = (const float*)d_in[14];
    const float* out1_b  = (const float*)d_in[15];
    const float* out2_w  = (const float*)d_in[16];
    const float* out2_b  = (const float*)d_in[17];

    float* ws     = (float*)d_ws;
    float* h      = ws;                               // 2M floats
    float* aggf   = h + (size_t)N_NODES * HID;        // 2M floats (fp32 final / fp16 agg alias)
    __half* agg16 = (__half*)aggf;
    __half* xh16  = (__half*)(aggf + (size_t)N_NODES * HID);  // 2M halves
    float* nxt    = aggf + (size_t)N_NODES * HID + (size_t)N_NODES * HID / 2;
    int2*  meta   = (int2*)nxt;
    int*   cnt    = (int*)(meta + N_EDGES);
    int*   rowptr = cnt + N_NODES;
    int*   wo     = rowptr + N_NODES + 1;
    float* gsum   = (float*)(wo + N_NODES);            // 64*128
    __half* ftab  = (__half*)(gsum + N_GRAPHS * 128);  // NL*TROWS*FILT halves
    __half* wpk   = ftab + (size_t)NL * TROWS * FILT;  // 20*16384 halves

    hipMemsetAsync(cnt, 0, N_NODES * sizeof(int), stream);
    hipMemsetAsync(gsum, 0, N_GRAPHS * 128 * sizeof(float), stream);
    k_embed<<<N_NODES * HID / 256, 256, 0, stream>>>(z, emb, h);
    k_hist<<<N_EDGES / 256, 256, 0, stream>>>(ei, cnt);
    k_scan<<<1, 1024, 0, stream>>>(cnt, rowptr, wo);
    k_scatter<<<N_EDGES / 256, 256, 0, stream>>>(ei, pos, wo, meta);
    k_tab2<<<NL * TROWS / 16, 256, 0, stream>>>(mlp1_w, mlp1_b, mlp2_w, mlp2_b, ftab);
    // fragment-pack weights: [0..5]=cl1, [6..11]=cl2, [12..17]=lin, 18=out1, 19=out2
    k_wpack<<<(6 * 2048 + 255) / 256, 256, 0, stream>>>(cl1_w, wpk, 6);
    k_wpack<<<(6 * 2048 + 255) / 256, 256, 0, stream>>>(cl2_w, wpk + (size_t)6 * 16384, 6);
    k_wpack<<<(6 * 2048 + 255) / 256, 256, 0, stream>>>(lin_w, wpk + (size_t)12 * 16384, 6);
    k_wpack<<<(2048 + 255) / 256, 256, 0, stream>>>(out1_w, wpk + (size_t)18 * 16384, 1);
    k_wpack<<<(2048 + 255) / 256, 256, 0, stream>>>(out2_w, wpk + (size_t)19 * 16384, 1);

    k_gemm0M2<<<N_NODES / 16, 256, 0, stream>>>(h, wpk, xh16);
    for (int i = 0; i < NL; ++i) {
        k_edge10<<<N_NODES / 4, 256, 0, stream>>>(
            meta, rowptr, xh16, ftab + (size_t)i * TROWS * FILT, agg16);
        if (i < NL - 1) {
            k_nodeM2<false, true, true><<<N_NODES / 16, 256, 0, stream>>>(
                agg16, nullptr,
                wpk + (size_t)(6 + i) * 16384, cl2_b + (size_t)i * HID,
                wpk + (size_t)(12 + i) * 16384, lin_b + (size_t)i * HID,
                h, h, wpk + (size_t)(i + 1) * 16384, xh16);
        } else {
            k_nodeM2<false, true, false><<<N_NODES / 16, 256, 0, stream>>>(
                agg16, nullptr,
                wpk + (size_t)(6 + i) * 16384, cl2_b + (size_t)i * HID,
                wpk + (size_t)(12 + i) * 16384, lin_b + (size_t)i * HID,
                h, h, nullptr, nullptr);
        }
    }
    // final MLP: fp32 A (h), output fp32 into aggf; then pool
    k_nodeM2<true, false, false><<<N_NODES / 16, 256, 0, stream>>>(
        nullptr, h, wpk + (size_t)18 * 16384, out1_b,
        wpk + (size_t)19 * 16384, out2_b, nullptr, aggf, nullptr, nullptr);
    k_pool2<<<N_NODES / 64, 128, 0, stream>>>(aggf, batch, gsum);
    k_div<<<N_GRAPHS, 128, 0, stream>>>(gsum, batch, (float*)d_out);
}